// Round 7
// baseline (627.158 us; speedup 1.0000x reference)
//
#include <hip/hip_runtime.h>
#include <hip/hip_bf16.h>
#include <hip/hip_cooperative_groups.h>

namespace cg = cooperative_groups;

#define IN_C 128
#define OUT_CH 128

typedef __attribute__((ext_vector_type(8))) short bf16x8;   // 8 bf16 = 4 VGPRs
typedef __attribute__((ext_vector_type(4))) float f32x4;

__device__ __forceinline__ unsigned pk2(float a, float b) {
    union { __hip_bfloat162 h; unsigned u; } c;
    c.h = __float22bfloat162_rn(make_float2(a, b));
    return c.u;
}
__device__ __forceinline__ float blo(unsigned v) { return __uint_as_float(v << 16); }
__device__ __forceinline__ float bhi(unsigned v) { return __uint_as_float(v & 0xffff0000u); }

__device__ __forceinline__ void add8(float* a, const uint4 v) {
    a[0] += blo(v.x); a[1] += bhi(v.x);
    a[2] += blo(v.y); a[3] += bhi(v.y);
    a[4] += blo(v.z); a[5] += bhi(v.z);
    a[6] += blo(v.w); a[7] += bhi(v.w);
}

// ============ cooperative build: prep + CSR in one launch ============
// P0 zero cnt, x->xb bf16 (+zero row N), Wcat=[Wl|Wr] bf16
// P1 count + per-edge position    P2 per-256-node-chunk padded sums
// P3 single-block exclusive scan  P4 offsets + pad-fill (pads -> row N)
// P5 bucket edges into CSR order
__global__ __launch_bounds__(256) void k_build(
        const float* __restrict__ x, const int* __restrict__ src,
        const int* __restrict__ dst, const float* __restrict__ Wl,
        const float* __restrict__ Wr, int* __restrict__ cnt,
        int* __restrict__ offs, int* __restrict__ bsum,
        int* __restrict__ pos, int* __restrict__ ebuf,
        unsigned short* __restrict__ Wcat, uint* __restrict__ xb,
        int N, int E, int useXb) {
    cg::grid_group grid = cg::this_grid();
    const int T   = gridDim.x * blockDim.x;
    const int tid = blockIdx.x * blockDim.x + threadIdx.x;
    __shared__ int sb[256];
    __shared__ int w4s[4];

    // ---- P0 ----
    for (int i = tid; i < N; i += T) cnt[i] = 0;
    if (useXb) {
        const int nx8 = (N + 1) * 16;
        for (int i = tid; i < nx8; i += T) {
            uint4 o = make_uint4(0u, 0u, 0u, 0u);
            if (i < N * 16) {
                const float4* p = reinterpret_cast<const float4*>(x + (size_t)i * 8);
                const float4 v0 = p[0], v1 = p[1];
                o.x = pk2(v0.x, v0.y); o.y = pk2(v0.z, v0.w);
                o.z = pk2(v1.x, v1.y); o.w = pk2(v1.z, v1.w);
            }
            reinterpret_cast<uint4*>(xb)[i] = o;
        }
    }
    for (int w = tid; w < 128 * 256; w += T) {
        const int n = w >> 8, k = w & 255;
        const float v = (k < IN_C) ? Wl[n * IN_C + k] : Wr[n * IN_C + (k - IN_C)];
        union { __hip_bfloat16 h; unsigned short s; } c;
        c.h = __float2bfloat16(v);
        Wcat[w] = c.s;
    }
    grid.sync();

    // ---- P1 ----
    for (int e = tid; e < E; e += T) pos[e] = atomicAdd(&cnt[dst[e]], 1);
    grid.sync();

    // ---- P2 ----
    const int nch = (N + 255) >> 8;
    if (blockIdx.x < (unsigned)nch) {
        const int i = blockIdx.x * 256 + threadIdx.x;
        int v = (i < N) ? ((cnt[i] + 3) & ~3) : 0;
        for (int d = 1; d < 64; d <<= 1) v += __shfl_xor(v, d);
        if ((threadIdx.x & 63) == 0) w4s[threadIdx.x >> 6] = v;
        __syncthreads();
        if (threadIdx.x == 0) bsum[blockIdx.x] = w4s[0] + w4s[1] + w4s[2] + w4s[3];
    }
    grid.sync();

    // ---- P3 ----
    if (blockIdx.x == 0) {
        const int t = threadIdx.x;
        const int v = (t < nch) ? bsum[t] : 0;
        sb[t] = v; __syncthreads();
        for (int d = 1; d < 256; d <<= 1) {
            const int u = (t >= d) ? sb[t - d] : 0;
            __syncthreads();
            sb[t] += u;
            __syncthreads();
        }
        if (t < nch) bsum[t] = sb[t] - v;   // exclusive
    }
    grid.sync();

    // ---- P4 ----
    if (blockIdx.x < (unsigned)nch) {
        const int t = threadIdx.x, i = blockIdx.x * 256 + t;
        const int c = (i < N) ? cnt[i] : 0;
        const int v = (c + 3) & ~3;
        sb[t] = v; __syncthreads();
        for (int d = 1; d < 256; d <<= 1) {
            const int u = (t >= d) ? sb[t - d] : 0;
            __syncthreads();
            sb[t] += u;
            __syncthreads();
        }
        if (i < N) {
            const int o = bsum[blockIdx.x] + sb[t] - v;
            offs[i] = o;
            for (int q = c; q < v; ++q) ebuf[o + q] = N;   // pads -> zero row
        }
    }
    grid.sync();

    // ---- P5 ----
    for (int e = tid; e < E; e += T) ebuf[offs[dst[e]] + pos[e]] = src[e];
}

// ============ fused gather-mean + MFMA GEMM + bias + L2 norm ============
// Block = 256 threads (4 waves), 16 nodes; lane -> (node group g = lane>>4,
// 16 B row chunk cl = lane&15). Gather is software-pipelined: eids prefetched
// 2 iterations ahead, row fragments double-buffered -> steady state has no
// exposed memory wait. eid over-reads land in ebuf's +16-int slack and are
// never used as row addresses.
template<bool BF16X>
__global__ __launch_bounds__(256) void k_sage(
        const float* __restrict__ x, const uint* __restrict__ xb,
        const int* __restrict__ ebuf, const int* __restrict__ offs,
        const int* __restrict__ cnt, const unsigned short* __restrict__ Wcat,
        const float* __restrict__ bl, float* __restrict__ out, int N) {
    __shared__ unsigned short feat[16][264];   // [0..255]=mean, [256..511]=x, +16B pad
    __shared__ float ssh[4][16];

    const int tid  = threadIdx.x;
    const int lane = tid & 63;
    const int wv   = tid >> 6;
    const int g    = lane >> 4;
    const int cl   = lane & 15;
    const int node0 = blockIdx.x * 16;
    const int nl   = wv * 4 + g;
    const int node = node0 + nl;

    int m = 0, off = 0;
    if (node < N) { off = offs[node]; m = cnt[node]; }
    const int mp = (m + 3) & ~3;

    float a[8];
#pragma unroll
    for (int i = 0; i < 8; ++i) a[i] = 0.f;

    if (BF16X) {
        const uint* rowb = xb + cl * 4;
        const int* ep = ebuf + off;
        if (mp > 0) {
            const int4 q0 = *reinterpret_cast<const int4*>(ep);
            uint4 r0x = *reinterpret_cast<const uint4*>(rowb + (size_t)q0.x * 64);
            uint4 r0y = *reinterpret_cast<const uint4*>(rowb + (size_t)q0.y * 64);
            uint4 r0z = *reinterpret_cast<const uint4*>(rowb + (size_t)q0.z * 64);
            uint4 r0w = *reinterpret_cast<const uint4*>(rowb + (size_t)q0.w * 64);
            int4 q1 = *reinterpret_cast<const int4*>(ep + 4);   // slack-safe
            for (int j = 4; j < mp; j += 4) {
                const int4 q2 = *reinterpret_cast<const int4*>(ep + j + 4);  // 2-ahead
                const uint4 r1x = *reinterpret_cast<const uint4*>(rowb + (size_t)q1.x * 64);
                const uint4 r1y = *reinterpret_cast<const uint4*>(rowb + (size_t)q1.y * 64);
                const uint4 r1z = *reinterpret_cast<const uint4*>(rowb + (size_t)q1.z * 64);
                const uint4 r1w = *reinterpret_cast<const uint4*>(rowb + (size_t)q1.w * 64);
                add8(a, r0x); add8(a, r0y); add8(a, r0z); add8(a, r0w);
                r0x = r1x; r0y = r1y; r0z = r1z; r0w = r1w;
                q1 = q2;
            }
            add8(a, r0x); add8(a, r0y); add8(a, r0z); add8(a, r0w);
        }
    } else {
        for (int j = 0; j < m; j += 4) {
            const int4 q = *reinterpret_cast<const int4*>(ebuf + off + j);
            const int qq[4] = {q.x, q.y, q.z, q.w};
#pragma unroll
            for (int t = 0; t < 4; ++t) {
                if (j + t < m) {
                    const float4* pr = reinterpret_cast<const float4*>(
                        x + (size_t)qq[t] * IN_C + cl * 8);
                    const float4 u0 = pr[0], u1 = pr[1];
                    a[0] += u0.x; a[1] += u0.y; a[2] += u0.z; a[3] += u0.w;
                    a[4] += u1.x; a[5] += u1.y; a[6] += u1.z; a[7] += u1.w;
                }
            }
        }
    }
    const float inv = 1.0f / fmaxf((float)m, 1.0f);
    uint4 pw;
    pw.x = pk2(a[0] * inv, a[1] * inv); pw.y = pk2(a[2] * inv, a[3] * inv);
    pw.z = pk2(a[4] * inv, a[5] * inv); pw.w = pk2(a[6] * inv, a[7] * inv);
    char* frow = reinterpret_cast<char*>(&feat[nl][0]);
    *reinterpret_cast<uint4*>(frow + cl * 16) = pw;

    uint4 xr = make_uint4(0u, 0u, 0u, 0u);
    if (node < N) {
        if (BF16X) {
            xr = *reinterpret_cast<const uint4*>(xb + (size_t)node * 64 + cl * 4);
        } else {
            const float4* pr = reinterpret_cast<const float4*>(
                x + (size_t)node * IN_C + cl * 8);
            const float4 u0 = pr[0], u1 = pr[1];
            xr.x = pk2(u0.x, u0.y); xr.y = pk2(u0.z, u0.w);
            xr.z = pk2(u1.x, u1.y); xr.w = pk2(u1.z, u1.w);
        }
    }
    *reinterpret_cast<uint4*>(frow + 256 + cl * 16) = xr;
    __syncthreads();

    // ---- MFMA: 16 nodes x 128 cols, K=256; wave wv -> cols [wv*32, wv*32+32) ----
    const int m_lane = lane & 15;
    const int kq = lane >> 4;
    f32x4 acc[2] = {{0, 0, 0, 0}, {0, 0, 0, 0}};
    const char* arow  = reinterpret_cast<const char*>(&feat[m_lane][0]) + kq * 16;
    const char* bbase = reinterpret_cast<const char*>(Wcat)
                      + (size_t)(wv * 32 + m_lane) * 512 + kq * 16;
#pragma unroll
    for (int ks = 0; ks < 8; ++ks) {
        const bf16x8 af = *reinterpret_cast<const bf16x8*>(arow + ks * 64);
        const bf16x8 b0 = *reinterpret_cast<const bf16x8*>(bbase + ks * 64);
        const bf16x8 b1 = *reinterpret_cast<const bf16x8*>(bbase + 16 * 512 + ks * 64);
        acc[0] = __builtin_amdgcn_mfma_f32_16x16x32_bf16(af, b0, acc[0], 0, 0, 0);
        acc[1] = __builtin_amdgcn_mfma_f32_16x16x32_bf16(af, b1, acc[1], 0, 0, 0);
    }

    const float bb0 = bl[wv * 32 + m_lane];
    const float bb1 = bl[wv * 32 + 16 + m_lane];
#pragma unroll
    for (int r = 0; r < 4; ++r) { acc[0][r] += bb0; acc[1][r] += bb1; }

    // sum of squares: 16-lane tree, then across 4 waves via LDS
#pragma unroll
    for (int r = 0; r < 4; ++r) {
        float v = acc[0][r] * acc[0][r] + acc[1][r] * acc[1][r];
        v += __shfl_xor(v, 1); v += __shfl_xor(v, 2);
        v += __shfl_xor(v, 4); v += __shfl_xor(v, 8);
        if (m_lane == 0) ssh[wv][kq * 4 + r] = v;
    }
    __syncthreads();

#pragma unroll
    for (int r = 0; r < 4; ++r) {
        const int nn = kq * 4 + r;
        const int nd = node0 + nn;
        if (nd < N) {
            const float ss = ssh[0][nn] + ssh[1][nn] + ssh[2][nn] + ssh[3][nn];
            const float rn = 1.0f / fmaxf(sqrtf(ss), 1e-12f);
            out[(size_t)nd * OUT_CH + wv * 32 + m_lane]      = acc[0][r] * rn;
            out[(size_t)nd * OUT_CH + wv * 32 + 16 + m_lane] = acc[1][r] * rn;
        }
    }
}

extern "C" void kernel_launch(void* const* d_in, const int* in_sizes, int n_in,
                              void* d_out, int out_size, void* d_ws, size_t ws_size,
                              hipStream_t stream) {
    const float* x    = (const float*)d_in[0];
    const int*   edge = (const int*)d_in[1];
    const float* Wl   = (const float*)d_in[2];
    const float* bl   = (const float*)d_in[3];
    const float* Wr   = (const float*)d_in[4];
    float*       out  = (float*)d_out;

    int N = in_sizes[0] / IN_C;
    int E = in_sizes[1] / 2;
    const int* src = edge;
    const int* dst = edge + E;

    // ws: cnt[N] | offs[N] | bsum[256] | pos[E] | ebuf[E+3N+16] | Wcat[32K bf16] | xb[(N+1)*128 bf16]
    char* p = (char*)d_ws;
    int* cnt  = (int*)p;            p += (size_t)N * 4;
    int* offs = (int*)p;            p += (size_t)N * 4;
    int* bsum = (int*)p;            p += 256 * 4;
    int* pos  = (int*)p;            p += (size_t)E * 4;
    int* ebuf = (int*)p;            p += ((size_t)E + 3 * (size_t)N + 16) * 4;
    unsigned short* Wcat = (unsigned short*)p;  p += 128 * 256 * 2;
    uint* xb = (uint*)p;
    const size_t need = (size_t)(p - (char*)d_ws) + ((size_t)N + 1) * IN_C * 2;
    int useXb = (ws_size >= need) ? 1 : 0;

    void* args[] = { (void*)&x, (void*)&src, (void*)&dst, (void*)&Wl, (void*)&Wr,
                     (void*)&cnt, (void*)&offs, (void*)&bsum, (void*)&pos,
                     (void*)&ebuf, (void*)&Wcat, (void*)&xb,
                     (void*)&N, (void*)&E, (void*)&useXb };
    hipLaunchCooperativeKernel((void*)k_build, dim3(1024), dim3(256), args, 0u, stream);

    const int blocksN = (N + 15) / 16;
    if (useXb)
        k_sage<true> <<<blocksN, 256, 0, stream>>>(x, xb, ebuf, offs, cnt, Wcat, bl, out, N);
    else
        k_sage<false><<<blocksN, 256, 0, stream>>>(x, xb, ebuf, offs, cnt, Wcat, bl, out, N);
}

// Round 8
// 140.084 us; speedup vs baseline: 4.4770x; 4.4770x over previous
//
#include <hip/hip_runtime.h>
#include <hip/hip_bf16.h>

#define IN_C 128
#define OUT_CH 128

typedef __attribute__((ext_vector_type(8))) short bf16x8;   // 8 bf16 = 4 VGPRs
typedef __attribute__((ext_vector_type(4))) float f32x4;

__device__ __forceinline__ unsigned pk2(float a, float b) {
    union { __hip_bfloat162 h; unsigned u; } c;
    c.h = __float22bfloat162_rn(make_float2(a, b));
    return c.u;
}
__device__ __forceinline__ float blo(unsigned v) { return __uint_as_float(v << 16); }
__device__ __forceinline__ float bhi(unsigned v) { return __uint_as_float(v & 0xffff0000u); }

__device__ __forceinline__ void add8(float* a, const uint4 v) {
    a[0] += blo(v.x); a[1] += bhi(v.x);
    a[2] += blo(v.y); a[3] += bhi(v.y);
    a[4] += blo(v.z); a[5] += bhi(v.z);
    a[6] += blo(v.w); a[7] += bhi(v.w);
}

// ---- fused prep (x->xb bf16 + zero row N, Wcat=[Wl|Wr] bf16) + edge count/pos ----
// Disjoint grid-stride index ranges: [0, NX8) xb chunks, [NX8, NX8+32768) Wcat,
// [NX8+32768, NX8+32768+E) edge count+pos.
__global__ __launch_bounds__(256) void k_prep_count(
        const float* __restrict__ x, const float* __restrict__ Wl,
        const float* __restrict__ Wr, const int* __restrict__ dst,
        uint* __restrict__ xb, unsigned short* __restrict__ Wcat,
        int* __restrict__ cnt, int* __restrict__ pos,
        int N, int E, int useXb) {
    const int NX8 = useXb ? (N + 1) * 16 : 0;
    const int WEND = NX8 + 128 * 256;
    const int TOT = WEND + E;
    const int T = gridDim.x * 256;
    for (int idx = blockIdx.x * 256 + threadIdx.x; idx < TOT; idx += T) {
        if (idx < NX8) {
            uint4 o = make_uint4(0u, 0u, 0u, 0u);
            if (idx < N * 16) {
                const float4* p = reinterpret_cast<const float4*>(x + (size_t)idx * 8);
                const float4 v0 = p[0], v1 = p[1];
                o.x = pk2(v0.x, v0.y); o.y = pk2(v0.z, v0.w);
                o.z = pk2(v1.x, v1.y); o.w = pk2(v1.z, v1.w);
            }
            reinterpret_cast<uint4*>(xb)[idx] = o;
        } else if (idx < WEND) {
            const int w = idx - NX8;
            const int n = w >> 8, k = w & 255;
            const float v = (k < IN_C) ? Wl[n * IN_C + k] : Wr[n * IN_C + (k - IN_C)];
            union { __hip_bfloat16 h; unsigned short s; } c;
            c.h = __float2bfloat16(v);
            Wcat[w] = c.s;
        } else {
            const int e = idx - WEND;
            pos[e] = atomicAdd(&cnt[dst[e]], 1);
        }
    }
}

// ---- padded exclusive offsets: per-block LDS scan + one atomicAdd for the base;
// also fills CSR pad slots with N (zero row). Chunk base order is atomic-dependent
// (permutes fp32 mean summation order only). ----
__global__ __launch_bounds__(256) void k_offs(
        const int* __restrict__ cnt, int* __restrict__ gtot,
        int* __restrict__ offs, int* __restrict__ ebuf, int N) {
    __shared__ int sb[256];
    __shared__ int base_s;
    const int t = threadIdx.x, i = blockIdx.x * 256 + t;
    const int c = (i < N) ? cnt[i] : 0;
    const int v = (c + 3) & ~3;
    sb[t] = v; __syncthreads();
    for (int d = 1; d < 256; d <<= 1) {
        const int u = (t >= d) ? sb[t - d] : 0;
        __syncthreads();
        sb[t] += u;
        __syncthreads();
    }
    if (t == 255) base_s = atomicAdd(gtot, sb[255]);
    __syncthreads();
    if (i < N) {
        const int o = base_s + sb[t] - v;
        offs[i] = o;
        for (int q = c; q < v; ++q) ebuf[o + q] = N;   // pads -> zero row
    }
}

__global__ __launch_bounds__(256) void k_bucket(
        const int* __restrict__ src, const int* __restrict__ dst,
        const int* __restrict__ pos, const int* __restrict__ offs,
        int* __restrict__ ebuf, int E) {
    int e = blockIdx.x * blockDim.x + threadIdx.x;
    if (e < E) ebuf[offs[dst[e]] + pos[e]] = src[e];
}

// ============ fused gather-mean + MFMA GEMM + bias + L2 norm ============
// Block = 256 threads (4 waves), 16 nodes; lane -> (node group g = lane>>4,
// 16 B row chunk cl = lane&15). Gather is software-pipelined: eids prefetched
// 2 iterations ahead, row fragments double-buffered -> steady state has no
// exposed memory wait. eid over-reads land in ebuf's slack and are never
// dereferenced as rows.
template<bool BF16X>
__global__ __launch_bounds__(256) void k_sage(
        const float* __restrict__ x, const uint* __restrict__ xb,
        const int* __restrict__ ebuf, const int* __restrict__ offs,
        const int* __restrict__ cnt, const unsigned short* __restrict__ Wcat,
        const float* __restrict__ bl, float* __restrict__ out, int N) {
    __shared__ unsigned short feat[16][264];   // [0..255]=mean, [256..511]=x, +16B pad
    __shared__ float ssh[4][16];

    const int tid  = threadIdx.x;
    const int lane = tid & 63;
    const int wv   = tid >> 6;
    const int g    = lane >> 4;
    const int cl   = lane & 15;
    const int node0 = blockIdx.x * 16;
    const int nl   = wv * 4 + g;
    const int node = node0 + nl;

    int m = 0, off = 0;
    if (node < N) { off = offs[node]; m = cnt[node]; }
    const int mp = (m + 3) & ~3;

    float a[8];
#pragma unroll
    for (int i = 0; i < 8; ++i) a[i] = 0.f;

    if (BF16X) {
        const uint* rowb = xb + cl * 4;
        const int* ep = ebuf + off;
        if (mp > 0) {
            const int4 q0 = *reinterpret_cast<const int4*>(ep);
            uint4 r0x = *reinterpret_cast<const uint4*>(rowb + (size_t)q0.x * 64);
            uint4 r0y = *reinterpret_cast<const uint4*>(rowb + (size_t)q0.y * 64);
            uint4 r0z = *reinterpret_cast<const uint4*>(rowb + (size_t)q0.z * 64);
            uint4 r0w = *reinterpret_cast<const uint4*>(rowb + (size_t)q0.w * 64);
            int4 q1 = *reinterpret_cast<const int4*>(ep + 4);   // slack-safe
            for (int j = 4; j < mp; j += 4) {
                const int4 q2 = *reinterpret_cast<const int4*>(ep + j + 4);  // 2-ahead
                const uint4 r1x = *reinterpret_cast<const uint4*>(rowb + (size_t)q1.x * 64);
                const uint4 r1y = *reinterpret_cast<const uint4*>(rowb + (size_t)q1.y * 64);
                const uint4 r1z = *reinterpret_cast<const uint4*>(rowb + (size_t)q1.z * 64);
                const uint4 r1w = *reinterpret_cast<const uint4*>(rowb + (size_t)q1.w * 64);
                add8(a, r0x); add8(a, r0y); add8(a, r0z); add8(a, r0w);
                r0x = r1x; r0y = r1y; r0z = r1z; r0w = r1w;
                q1 = q2;
            }
            add8(a, r0x); add8(a, r0y); add8(a, r0z); add8(a, r0w);
        }
    } else {
        for (int j = 0; j < m; j += 4) {
            const int4 q = *reinterpret_cast<const int4*>(ebuf + off + j);
            const int qq[4] = {q.x, q.y, q.z, q.w};
#pragma unroll
            for (int t = 0; t < 4; ++t) {
                if (j + t < m) {
                    const float4* pr = reinterpret_cast<const float4*>(
                        x + (size_t)qq[t] * IN_C + cl * 8);
                    const float4 u0 = pr[0], u1 = pr[1];
                    a[0] += u0.x; a[1] += u0.y; a[2] += u0.z; a[3] += u0.w;
                    a[4] += u1.x; a[5] += u1.y; a[6] += u1.z; a[7] += u1.w;
                }
            }
        }
    }
    const float inv = 1.0f / fmaxf((float)m, 1.0f);
    uint4 pw;
    pw.x = pk2(a[0] * inv, a[1] * inv); pw.y = pk2(a[2] * inv, a[3] * inv);
    pw.z = pk2(a[4] * inv, a[5] * inv); pw.w = pk2(a[6] * inv, a[7] * inv);
    char* frow = reinterpret_cast<char*>(&feat[nl][0]);
    *reinterpret_cast<uint4*>(frow + cl * 16) = pw;

    uint4 xr = make_uint4(0u, 0u, 0u, 0u);
    if (node < N) {
        if (BF16X) {
            xr = *reinterpret_cast<const uint4*>(xb + (size_t)node * 64 + cl * 4);
        } else {
            const float4* pr = reinterpret_cast<const float4*>(
                x + (size_t)node * IN_C + cl * 8);
            const float4 u0 = pr[0], u1 = pr[1];
            xr.x = pk2(u0.x, u0.y); xr.y = pk2(u0.z, u0.w);
            xr.z = pk2(u1.x, u1.y); xr.w = pk2(u1.z, u1.w);
        }
    }
    *reinterpret_cast<uint4*>(frow + 256 + cl * 16) = xr;
    __syncthreads();

    // ---- MFMA: 16 nodes x 128 cols, K=256; wave wv -> cols [wv*32, wv*32+32) ----
    const int m_lane = lane & 15;
    const int kq = lane >> 4;
    f32x4 acc[2] = {{0, 0, 0, 0}, {0, 0, 0, 0}};
    const char* arow  = reinterpret_cast<const char*>(&feat[m_lane][0]) + kq * 16;
    const char* bbase = reinterpret_cast<const char*>(Wcat)
                      + (size_t)(wv * 32 + m_lane) * 512 + kq * 16;
#pragma unroll
    for (int ks = 0; ks < 8; ++ks) {
        const bf16x8 af = *reinterpret_cast<const bf16x8*>(arow + ks * 64);
        const bf16x8 b0 = *reinterpret_cast<const bf16x8*>(bbase + ks * 64);
        const bf16x8 b1 = *reinterpret_cast<const bf16x8*>(bbase + 16 * 512 + ks * 64);
        acc[0] = __builtin_amdgcn_mfma_f32_16x16x32_bf16(af, b0, acc[0], 0, 0, 0);
        acc[1] = __builtin_amdgcn_mfma_f32_16x16x32_bf16(af, b1, acc[1], 0, 0, 0);
    }

    const float bb0 = bl[wv * 32 + m_lane];
    const float bb1 = bl[wv * 32 + 16 + m_lane];
#pragma unroll
    for (int r = 0; r < 4; ++r) { acc[0][r] += bb0; acc[1][r] += bb1; }

    // sum of squares: 16-lane tree, then across 4 waves via LDS
#pragma unroll
    for (int r = 0; r < 4; ++r) {
        float v = acc[0][r] * acc[0][r] + acc[1][r] * acc[1][r];
        v += __shfl_xor(v, 1); v += __shfl_xor(v, 2);
        v += __shfl_xor(v, 4); v += __shfl_xor(v, 8);
        if (m_lane == 0) ssh[wv][kq * 4 + r] = v;
    }
    __syncthreads();

#pragma unroll
    for (int r = 0; r < 4; ++r) {
        const int nn = kq * 4 + r;
        const int nd = node0 + nn;
        if (nd < N) {
            const float ss = ssh[0][nn] + ssh[1][nn] + ssh[2][nn] + ssh[3][nn];
            const float rn = 1.0f / fmaxf(sqrtf(ss), 1e-12f);
            out[(size_t)nd * OUT_CH + wv * 32 + m_lane]      = acc[0][r] * rn;
            out[(size_t)nd * OUT_CH + wv * 32 + 16 + m_lane] = acc[1][r] * rn;
        }
    }
}

extern "C" void kernel_launch(void* const* d_in, const int* in_sizes, int n_in,
                              void* d_out, int out_size, void* d_ws, size_t ws_size,
                              hipStream_t stream) {
    const float* x    = (const float*)d_in[0];
    const int*   edge = (const int*)d_in[1];
    const float* Wl   = (const float*)d_in[2];
    const float* bl   = (const float*)d_in[3];
    const float* Wr   = (const float*)d_in[4];
    float*       out  = (float*)d_out;

    const int N = in_sizes[0] / IN_C;
    const int E = in_sizes[1] / 2;
    const int* src = edge;
    const int* dst = edge + E;

    // ws: cnt[N] | gtot[4] | offs[N] | pos[E] | ebuf[E+3N+32] | Wcat[32K bf16] | xb[(N+1)*128 bf16]
    char* p = (char*)d_ws;
    int* cnt  = (int*)p;            p += (size_t)N * 4;
    int* gtot = (int*)p;            p += 4 * 4;
    int* offs = (int*)p;            p += (size_t)N * 4;
    int* pos  = (int*)p;            p += (size_t)E * 4;
    int* ebuf = (int*)p;            p += ((size_t)E + 3 * (size_t)N + 32) * 4;
    unsigned short* Wcat = (unsigned short*)p;  p += 128 * 256 * 2;
    uint* xb = (uint*)p;
    const size_t need = (size_t)(p - (char*)d_ws) + ((size_t)N + 1) * IN_C * 2;
    const int useXb = (ws_size >= need) ? 1 : 0;

    hipMemsetAsync(cnt, 0, ((size_t)N + 4) * 4, stream);   // cnt + gtot

    const int NX8  = useXb ? (N + 1) * 16 : 0;
    const int totA = NX8 + 128 * 256 + E;
    k_prep_count<<<(totA + 255) / 256, 256, 0, stream>>>(
        x, Wl, Wr, dst, xb, Wcat, cnt, pos, N, E, useXb);

    const int nch = (N + 255) / 256;
    k_offs  <<<nch, 256, 0, stream>>>(cnt, gtot, offs, ebuf, N);
    k_bucket<<<(E + 255) / 256, 256, 0, stream>>>(src, dst, pos, offs, ebuf, E);

    const int blocksN = (N + 15) / 16;
    if (useXb)
        k_sage<true> <<<blocksN, 256, 0, stream>>>(x, xb, ebuf, offs, cnt, Wcat, bl, out, N);
    else
        k_sage<false><<<blocksN, 256, 0, stream>>>(x, xb, ebuf, offs, cnt, Wcat, bl, out, N);
}

// Round 10
// 134.482 us; speedup vs baseline: 4.6635x; 1.0417x over previous
//
#include <hip/hip_runtime.h>
#include <hip/hip_bf16.h>

#define IN_C 128
#define OUT_CH 128
#define NCOPY 8
#define POSMASK 0x0FFFFFFF

typedef __attribute__((ext_vector_type(8))) short bf16x8;   // 8 bf16 = 4 VGPRs
typedef __attribute__((ext_vector_type(4))) float f32x4;

__device__ __forceinline__ unsigned pk2(float a, float b) {
    union { __hip_bfloat162 h; unsigned u; } c;
    c.h = __float22bfloat162_rn(make_float2(a, b));
    return c.u;
}
__device__ __forceinline__ float blo(unsigned v) { return __uint_as_float(v << 16); }
__device__ __forceinline__ float bhi(unsigned v) { return __uint_as_float(v & 0xffff0000u); }

__device__ __forceinline__ void add8(float* a, const uint4 v) {
    a[0] += blo(v.x); a[1] += bhi(v.x);
    a[2] += blo(v.y); a[3] += bhi(v.y);
    a[4] += blo(v.z); a[5] += bhi(v.z);
    a[6] += blo(v.w); a[7] += bhi(v.w);
}

// ---- fused prep (x->xb bf16 + zero row N, Wcat=[Wl|Wr] bf16) + edge count/pos ----
// Count uses 8-way replicated counters cnt8[c][N], c = blockIdx&7, to cut
// same-address and same-cacheline atomic serialization ~8x. pos packs the
// copy index in bits 28..31.
__global__ __launch_bounds__(256) void k_prep_count(
        const float* __restrict__ x, const float* __restrict__ Wl,
        const float* __restrict__ Wr, const int* __restrict__ dst,
        uint* __restrict__ xb, unsigned short* __restrict__ Wcat,
        int* __restrict__ cnt8, int* __restrict__ pos,
        int N, int E, int useXb) {
    const int NX8 = useXb ? (N + 1) * 16 : 0;
    const int WEND = NX8 + 128 * 256;
    const int TOT = WEND + E;
    const int T = gridDim.x * 256;
    int* mycnt = cnt8 + (size_t)(blockIdx.x & (NCOPY - 1)) * N;
    const int ctag = (blockIdx.x & (NCOPY - 1)) << 28;
    for (int idx = blockIdx.x * 256 + threadIdx.x; idx < TOT; idx += T) {
        if (idx < NX8) {
            uint4 o = make_uint4(0u, 0u, 0u, 0u);
            if (idx < N * 16) {
                const float4* p = reinterpret_cast<const float4*>(x + (size_t)idx * 8);
                const float4 v0 = p[0], v1 = p[1];
                o.x = pk2(v0.x, v0.y); o.y = pk2(v0.z, v0.w);
                o.z = pk2(v1.x, v1.y); o.w = pk2(v1.z, v1.w);
            }
            reinterpret_cast<uint4*>(xb)[idx] = o;
        } else if (idx < WEND) {
            const int w = idx - NX8;
            const int n = w >> 8, k = w & 255;
            const float v = (k < IN_C) ? Wl[n * IN_C + k] : Wr[n * IN_C + (k - IN_C)];
            union { __hip_bfloat16 h; unsigned short s; } cc;
            cc.h = __float2bfloat16(v);
            Wcat[w] = cc.s;
        } else {
            const int e = idx - WEND;
            pos[e] = atomicAdd(&mycnt[dst[e]], 1) | ctag;
        }
    }
}

// ---- padded exclusive offsets over per-node totals (sum of 8 copies).
// Per-block LDS scan + one global atomicAdd for the block base (order-dependent
// base permutes fp32 mean summation order only; spans are NOT derived from
// offs differences anywhere). Rewrites cnt8[c][i] in place as that copy's
// running start; writes real degree to degs[i]; fills CSR pad slots with N. ----
__global__ __launch_bounds__(256) void k_offs(
        int* __restrict__ cnt8, int* __restrict__ gtot,
        int* __restrict__ offs, int* __restrict__ degs,
        int* __restrict__ ebuf, int N) {
    __shared__ int sb[256];
    __shared__ int base_s;
    const int t = threadIdx.x, i = blockIdx.x * 256 + t;
    int cc[NCOPY];
    int tot = 0;
    if (i < N) {
#pragma unroll
        for (int c = 0; c < NCOPY; ++c) { cc[c] = cnt8[(size_t)c * N + i]; tot += cc[c]; }
    }
    const int v = (tot + 3) & ~3;
    sb[t] = v; __syncthreads();
    for (int d = 1; d < 256; d <<= 1) {
        const int u = (t >= d) ? sb[t - d] : 0;
        __syncthreads();
        sb[t] += u;
        __syncthreads();
    }
    if (t == 255) base_s = atomicAdd(gtot, sb[255]);
    __syncthreads();
    if (i < N) {
        const int o = base_s + sb[t] - v;
        offs[i] = o;
        degs[i] = tot;
        int run = o;
#pragma unroll
        for (int c = 0; c < NCOPY; ++c) { cnt8[(size_t)c * N + i] = run; run += cc[c]; }
        for (int q = tot; q < v; ++q) ebuf[o + q] = N;   // pads -> zero row
    }
}

__global__ __launch_bounds__(256) void k_bucket(
        const int* __restrict__ src, const int* __restrict__ dst,
        const int* __restrict__ pos, const int* __restrict__ cnt8,
        int* __restrict__ ebuf, int N, int E) {
    int e = blockIdx.x * blockDim.x + threadIdx.x;
    if (e < E) {
        const int p = pos[e];
        const int c = ((unsigned)p) >> 28;
        ebuf[cnt8[(size_t)c * N + dst[e]] + (p & POSMASK)] = src[e];
    }
}

// ============ fused gather-mean + MFMA GEMM + bias + L2 norm ============
// Block = 256 threads (4 waves), 16 nodes; lane -> (node group g = lane>>4,
// 16 B row chunk cl = lane&15). Gather is software-pipelined: eids prefetched
// 2 iterations ahead, row fragments double-buffered. Per-node span = padded
// degree (pads index the all-zero row N in the bf16 path, skipped via q<N in
// the fp32 path) — NEVER offs[i+1]-offs[i] (offs is non-monotone across
// 256-node chunks because chunk bases come from an atomic). eid over-reads
// land in ebuf slack and are never dereferenced as rows.
template<bool BF16X>
__global__ __launch_bounds__(256) void k_sage(
        const float* __restrict__ x, const uint* __restrict__ xb,
        const int* __restrict__ ebuf, const int* __restrict__ offs,
        const int* __restrict__ degs, const unsigned short* __restrict__ Wcat,
        const float* __restrict__ bl, float* __restrict__ out, int N) {
    __shared__ unsigned short feat[16][264];   // [0..255]=mean, [256..511]=x, +16B pad
    __shared__ float ssh[4][16];

    const int tid  = threadIdx.x;
    const int lane = tid & 63;
    const int wv   = tid >> 6;
    const int g    = lane >> 4;
    const int cl   = lane & 15;
    const int node0 = blockIdx.x * 16;
    const int nl   = wv * 4 + g;
    const int node = node0 + nl;

    int m = 0, off = 0;
    if (node < N) { off = offs[node]; m = degs[node]; }
    const int mp = (m + 3) & ~3;   // padded span

    float a[8];
#pragma unroll
    for (int i = 0; i < 8; ++i) a[i] = 0.f;

    if (BF16X) {
        const uint* rowb = xb + cl * 4;
        const int* ep = ebuf + off;
        if (mp > 0) {
            const int4 q0 = *reinterpret_cast<const int4*>(ep);
            uint4 r0x = *reinterpret_cast<const uint4*>(rowb + (size_t)q0.x * 64);
            uint4 r0y = *reinterpret_cast<const uint4*>(rowb + (size_t)q0.y * 64);
            uint4 r0z = *reinterpret_cast<const uint4*>(rowb + (size_t)q0.z * 64);
            uint4 r0w = *reinterpret_cast<const uint4*>(rowb + (size_t)q0.w * 64);
            int4 q1 = *reinterpret_cast<const int4*>(ep + 4);   // slack-safe
            for (int j = 4; j < mp; j += 4) {
                const int4 q2 = *reinterpret_cast<const int4*>(ep + j + 4);  // 2-ahead
                const uint4 r1x = *reinterpret_cast<const uint4*>(rowb + (size_t)q1.x * 64);
                const uint4 r1y = *reinterpret_cast<const uint4*>(rowb + (size_t)q1.y * 64);
                const uint4 r1z = *reinterpret_cast<const uint4*>(rowb + (size_t)q1.z * 64);
                const uint4 r1w = *reinterpret_cast<const uint4*>(rowb + (size_t)q1.w * 64);
                add8(a, r0x); add8(a, r0y); add8(a, r0z); add8(a, r0w);
                r0x = r1x; r0y = r1y; r0z = r1z; r0w = r1w;
                q1 = q2;
            }
            add8(a, r0x); add8(a, r0y); add8(a, r0z); add8(a, r0w);
        }
    } else {
        for (int j = 0; j < mp; j += 4) {
            const int4 q = *reinterpret_cast<const int4*>(ebuf + off + j);
            const int qq[4] = {q.x, q.y, q.z, q.w};
#pragma unroll
            for (int t = 0; t < 4; ++t) {
                if (qq[t] < N) {
                    const float4* pr = reinterpret_cast<const float4*>(
                        x + (size_t)qq[t] * IN_C + cl * 8);
                    const float4 u0 = pr[0], u1 = pr[1];
                    a[0] += u0.x; a[1] += u0.y; a[2] += u0.z; a[3] += u0.w;
                    a[4] += u1.x; a[5] += u1.y; a[6] += u1.z; a[7] += u1.w;
                }
            }
        }
    }
    const float inv = 1.0f / fmaxf((float)m, 1.0f);
    uint4 pw;
    pw.x = pk2(a[0] * inv, a[1] * inv); pw.y = pk2(a[2] * inv, a[3] * inv);
    pw.z = pk2(a[4] * inv, a[5] * inv); pw.w = pk2(a[6] * inv, a[7] * inv);
    char* frow = reinterpret_cast<char*>(&feat[nl][0]);
    *reinterpret_cast<uint4*>(frow + cl * 16) = pw;

    uint4 xr = make_uint4(0u, 0u, 0u, 0u);
    if (node < N) {
        if (BF16X) {
            xr = *reinterpret_cast<const uint4*>(xb + (size_t)node * 64 + cl * 4);
        } else {
            const float4* pr = reinterpret_cast<const float4*>(
                x + (size_t)node * IN_C + cl * 8);
            const float4 u0 = pr[0], u1 = pr[1];
            xr.x = pk2(u0.x, u0.y); xr.y = pk2(u0.z, u0.w);
            xr.z = pk2(u1.x, u1.y); xr.w = pk2(u1.z, u1.w);
        }
    }
    *reinterpret_cast<uint4*>(frow + 256 + cl * 16) = xr;
    __syncthreads();

    // ---- MFMA: 16 nodes x 128 cols, K=256; wave wv -> cols [wv*32, wv*32+32) ----
    const int m_lane = lane & 15;
    const int kq = lane >> 4;
    f32x4 acc[2] = {{0, 0, 0, 0}, {0, 0, 0, 0}};
    const char* arow  = reinterpret_cast<const char*>(&feat[m_lane][0]) + kq * 16;
    const char* bbase = reinterpret_cast<const char*>(Wcat)
                      + (size_t)(wv * 32 + m_lane) * 512 + kq * 16;
#pragma unroll
    for (int ks = 0; ks < 8; ++ks) {
        const bf16x8 af = *reinterpret_cast<const bf16x8*>(arow + ks * 64);
        const bf16x8 b0 = *reinterpret_cast<const bf16x8*>(bbase + ks * 64);
        const bf16x8 b1 = *reinterpret_cast<const bf16x8*>(bbase + 16 * 512 + ks * 64);
        acc[0] = __builtin_amdgcn_mfma_f32_16x16x32_bf16(af, b0, acc[0], 0, 0, 0);
        acc[1] = __builtin_amdgcn_mfma_f32_16x16x32_bf16(af, b1, acc[1], 0, 0, 0);
    }

    const float bb0 = bl[wv * 32 + m_lane];
    const float bb1 = bl[wv * 32 + 16 + m_lane];
#pragma unroll
    for (int r = 0; r < 4; ++r) { acc[0][r] += bb0; acc[1][r] += bb1; }

    // sum of squares: 16-lane tree, then across 4 waves via LDS
#pragma unroll
    for (int r = 0; r < 4; ++r) {
        float v = acc[0][r] * acc[0][r] + acc[1][r] * acc[1][r];
        v += __shfl_xor(v, 1); v += __shfl_xor(v, 2);
        v += __shfl_xor(v, 4); v += __shfl_xor(v, 8);
        if (m_lane == 0) ssh[wv][kq * 4 + r] = v;
    }
    __syncthreads();

#pragma unroll
    for (int r = 0; r < 4; ++r) {
        const int nn = kq * 4 + r;
        const int nd = node0 + nn;
        if (nd < N) {
            const float ss = ssh[0][nn] + ssh[1][nn] + ssh[2][nn] + ssh[3][nn];
            const float rn = 1.0f / fmaxf(sqrtf(ss), 1e-12f);
            out[(size_t)nd * OUT_CH + wv * 32 + m_lane]      = acc[0][r] * rn;
            out[(size_t)nd * OUT_CH + wv * 32 + 16 + m_lane] = acc[1][r] * rn;
        }
    }
}

extern "C" void kernel_launch(void* const* d_in, const int* in_sizes, int n_in,
                              void* d_out, int out_size, void* d_ws, size_t ws_size,
                              hipStream_t stream) {
    const float* x    = (const float*)d_in[0];
    const int*   edge = (const int*)d_in[1];
    const float* Wl   = (const float*)d_in[2];
    const float* bl   = (const float*)d_in[3];
    const float* Wr   = (const float*)d_in[4];
    float*       out  = (float*)d_out;

    const int N = in_sizes[0] / IN_C;
    const int E = in_sizes[1] / 2;
    const int* src = edge;
    const int* dst = edge + E;

    // ws: cnt8[8N] | gtot[4] | offs[N] | degs[N] | pos[E] | ebuf[E+3N+32]
    //   | Wcat[32K bf16] | xb[(N+1)*128 bf16]
    char* p = (char*)d_ws;
    int* cnt8 = (int*)p;            p += (size_t)NCOPY * N * 4;
    int* gtot = (int*)p;            p += 4 * 4;
    int* offs = (int*)p;            p += (size_t)N * 4;
    int* degs = (int*)p;            p += (size_t)N * 4;
    int* pos  = (int*)p;            p += (size_t)E * 4;
    int* ebuf = (int*)p;            p += ((size_t)E + 3 * (size_t)N + 32) * 4;
    unsigned short* Wcat = (unsigned short*)p;  p += 128 * 256 * 2;
    uint* xb = (uint*)p;
    const size_t need = (size_t)(p - (char*)d_ws) + ((size_t)N + 1) * IN_C * 2;
    const int useXb = (ws_size >= need) ? 1 : 0;

    hipMemsetAsync(cnt8, 0, ((size_t)NCOPY * N + 4) * 4, stream);   // cnt8 + gtot

    const int NX8  = useXb ? (N + 1) * 16 : 0;
    const int totA = NX8 + 128 * 256 + E;
    k_prep_count<<<(totA + 255) / 256, 256, 0, stream>>>(
        x, Wl, Wr, dst, xb, Wcat, cnt8, pos, N, E, useXb);

    const int nch = (N + 255) / 256;
    k_offs  <<<nch, 256, 0, stream>>>(cnt8, gtot, offs, degs, ebuf, N);
    k_bucket<<<(E + 255) / 256, 256, 0, stream>>>(src, dst, pos, cnt8, ebuf, N, E);

    const int blocksN = (N + 15) / 16;
    if (useXb)
        k_sage<true> <<<blocksN, 256, 0, stream>>>(x, xb, ebuf, offs, degs, Wcat, bl, out, N);
    else
        k_sage<false><<<blocksN, 256, 0, stream>>>(x, xb, ebuf, offs, degs, Wcat, bl, out, N);
}